// Round 13
// baseline (46.741 us; speedup 1.0000x reference)
//
#include <hip/hip_runtime.h>
#include <math.h>

#define NFEAT 768
#define NT    128   // 2 waves/block, 1 wave = 1 element, ZERO barriers

typedef float f2 __attribute__((ext_vector_type(2)));
#define MEMFENCE() asm volatile("" ::: "memory")

// bit0-preserving GF2-linear swizzle: addr bits 3..1 ^= index bits 6..4.
__device__ __forceinline__ int swz2(int j){ return j ^ ((j >> 3) & 0xE); }

// Composite of the CNOT ring CNOT(0,1),...,CNOT(9,0): s_after[j] = s_before[perm(j)]. GF2-linear.
__device__ __forceinline__ int cnot_perm(int j){
  int i = j;
  i ^= ((i >> 0) & 1) << 9;
  i ^= ((i >> 1) & 1) << 0;
  i ^= ((i >> 2) & 1) << 1;
  i ^= ((i >> 3) & 1) << 2;
  i ^= ((i >> 4) & 1) << 3;
  i ^= ((i >> 5) & 1) << 4;
  i ^= ((i >> 6) & 1) << 5;
  i ^= ((i >> 7) & 1) << 6;
  i ^= ((i >> 8) & 1) << 7;
  i ^= ((i >> 9) & 1) << 8;
  return i;
}

// ---- DPP cross-lane (VALU pipe): quad_perm xor1=0xB1, xor2=0x4E ----
template<int CTRL>
__device__ __forceinline__ float dpp_mov(float x){
  return __builtin_bit_cast(float,
    __builtin_amdgcn_update_dpp(0, __builtin_bit_cast(int, x), CTRL, 0xF, 0xF, true));
}
template<int CTRL>
__device__ __forceinline__ float dpp_add(float x){ return x + dpp_mov<CTRL>(x); }

// ---- packed-f32 primitives (VOP3P) — ALL hot-path f2 math forced to pk ----
__device__ __forceinline__ f2 pk_add(f2 a, f2 b){
  f2 d; asm("v_pk_add_f32 %0, %1, %2" : "=v"(d) : "v"(a), "v"(b)); return d;
}
__device__ __forceinline__ f2 pk_sub(f2 a, f2 b){
  f2 d; asm("v_pk_add_f32 %0, %1, %2 neg_lo:[0,1] neg_hi:[0,1]" : "=v"(d) : "v"(a), "v"(b)); return d;
}
__device__ __forceinline__ f2 pk_mul2(f2 a, f2 b){
  f2 d; asm("v_pk_mul_f32 %0, %1, %2" : "=v"(d) : "v"(a), "v"(b)); return d;
}
__device__ __forceinline__ f2 pk_fma2(f2 a, f2 b, f2 c){
  f2 d; asm("v_pk_fma_f32 %0, %1, %2, %3" : "=v"(d) : "v"(a), "v"(b), "v"(c)); return d;
}
__device__ __forceinline__ f2 pk_cmul(f2 s, f2 v){
  f2 d;
  asm("v_pk_mul_f32 %0, %1, %2 op_sel:[0,0] op_sel_hi:[0,1]\n\t"
      "v_pk_fma_f32 %0, %1, %2, %0 op_sel:[1,1,0] op_sel_hi:[1,0,1] neg_lo:[0,1,0]"
      : "=&v"(d) : "v"(s), "v"(v));
  return d;
}
__device__ __forceinline__ f2 pk_cfma(f2 s, f2 v, f2 acc){
  f2 d;
  asm("v_pk_fma_f32 %0, %2, %3, %1 op_sel:[0,0,0] op_sel_hi:[0,1,1]\n\t"
      "v_pk_fma_f32 %0, %2, %3, %0 op_sel:[1,1,0] op_sel_hi:[1,0,1] neg_lo:[0,1,0]"
      : "=&v"(d) : "v"(acc), "v"(s), "v"(v));
  return d;
}
// d = acc + (a.r*b.i, -a.i*b.r)
__device__ __forceinline__ f2 pk_cross(f2 a, f2 b, f2 acc){
  f2 d;
  asm("v_pk_fma_f32 %0, %2, %3, %1 op_sel:[0,1,0] op_sel_hi:[1,0,1] neg_hi:[1,0,0]"
      : "=&v"(d) : "v"(acc), "v"(a), "v"(b));
  return d;
}
__device__ __forceinline__ void pk_ry(f2 cs, f2& a, f2& b){
  f2 t1, t2, na, nb;
  asm("v_pk_mul_f32 %0, %2, %3 op_sel:[1,0] op_sel_hi:[1,1] neg_lo:[1,0] neg_hi:[1,0]\n\t"
      "v_pk_mul_f32 %1, %2, %4 op_sel:[1,0] op_sel_hi:[1,1]"
      : "=&v"(t1), "=&v"(t2) : "v"(cs), "v"(b), "v"(a));
  asm("v_pk_fma_f32 %0, %2, %3, %4 op_sel:[0,0,0] op_sel_hi:[0,1,1]\n\t"
      "v_pk_fma_f32 %1, %2, %5, %6 op_sel:[0,0,0] op_sel_hi:[0,1,1]"
      : "=&v"(na), "=&v"(nb) : "v"(cs), "v"(a), "v"(t1), "v"(b), "v"(t2));
  a = na; b = nb;
}
__device__ __forceinline__ void gateU(const f2* g, f2& a, f2& b){
  const f2 na = pk_cfma(g[1], b, pk_cmul(g[0], a));
  const f2 nb = pk_cfma(g[3], b, pk_cmul(g[2], a));
  a = na; b = nb;
}
__device__ __forceinline__ f2 rot90(f2 v){ return f2{-v.y, v.x}; }
__device__ __forceinline__ void bfly(f2& a, f2& b, f2 tw){
  const f2 u = pk_add(a, b), v = pk_sub(a, b);
  a = u; b = pk_cmul(tw, v);
}
__device__ __forceinline__ void bfly1(f2& a, f2& b){
  const f2 u = pk_add(a, b), v = pk_sub(a, b); a = u; b = v;
}
__device__ __forceinline__ void bflyI(f2& a, f2& b){
  const f2 u = pk_add(a, b), v = pk_sub(a, b); a = u; b = f2{-v.y, v.x};
}

template<int MASK>
__device__ __forceinline__ void gate_on(f2* xv, const f2* g){
  #pragma unroll
  for (int m = 0; m < 16; ++m) if (!(m & MASK)) gateU(g, xv[m], xv[m|MASK]);
}
template<int MASK>
__device__ __forceinline__ void ry_on(f2* xv, const f2 cs){
  #pragma unroll
  for (int m = 0; m < 16; ++m) if (!(m & MASK)) pk_ry(cs, xv[m], xv[m|MASK]);
}
template<int MASK>
__device__ __forceinline__ f2 pairsum16(const f2* z){
  f2 rp = {0.f, 0.f}, ip = {0.f, 0.f};
  #pragma unroll
  for (int m = 0; m < 16; ++m) if (!(m & MASK)){
    rp = pk_fma2(z[m], z[m|MASK], rp);
    ip = pk_cross(z[m], z[m|MASK], ip);
  }
  return f2{ rp.x + rp.y, ip.x + ip.y };
}

// ---- b128-paired LDS I/O (layouts A'/B'/C' as in R10/R12) ----
__device__ __forceinline__ void rdA(const f2* bb, int a0, f2* xv){
  #pragma unroll
  for (int k = 0; k < 8; ++k){
    const float4 v = *(const float4*)(bb + (a0 ^ (k << 7)));
    xv[2*k] = f2{v.x, v.y}; xv[2*k+1] = f2{v.z, v.w};
  }
}
__device__ __forceinline__ void wrA(f2* bb, int a0, const f2* xv){
  #pragma unroll
  for (int k = 0; k < 8; ++k)
    *(float4*)(bb + (a0 ^ (k << 7))) = make_float4(xv[2*k].x, xv[2*k].y, xv[2*k+1].x, xv[2*k+1].y);
}
__device__ __forceinline__ void rdB(const f2* bb, int a0, f2* xv){
  #pragma unroll
  for (int k = 0; k < 8; ++k){
    const float4 v = *(const float4*)(bb + (a0 ^ ((k << 4) | (k << 1))));
    xv[2*k] = f2{v.x, v.y}; xv[2*k+1] = f2{v.z, v.w};
  }
}
__device__ __forceinline__ void wrB(f2* bb, int a0, const f2* xv){
  #pragma unroll
  for (int k = 0; k < 8; ++k)
    *(float4*)(bb + (a0 ^ ((k << 4) | (k << 1)))) = make_float4(xv[2*k].x, xv[2*k].y, xv[2*k+1].x, xv[2*k+1].y);
}
__device__ __forceinline__ void rdC(const f2* bb, int a0, f2* xv){
  #pragma unroll
  for (int k = 0; k < 8; ++k){
    const float4 v = *(const float4*)(bb + (a0 ^ (k << 1)));
    xv[2*k] = f2{v.x, v.y}; xv[2*k+1] = f2{v.z, v.w};
  }
}
__device__ __forceinline__ void wrC(f2* bb, int a0, const f2* xv){
  #pragma unroll
  for (int k = 0; k < 8; ++k)
    *(float4*)(bb + (a0 ^ (k << 1))) = make_float4(xv[2*k].x, xv[2*k].y, xv[2*k+1].x, xv[2*k+1].y);
}

__global__ void gate_prep(const float* __restrict__ w, float* __restrict__ gt){
  const int t = threadIdx.x;
  if (t >= 10) return;
  const float ha = 0.5f*w[t*4+0], hb = 0.5f*w[t*4+1];
  const float hg = 0.5f*w[t*4+2], hd = 0.5f*w[t*4+3];
  const float ca = cosf(ha), sa = sinf(ha);
  const float cb = cosf(hb), sb = sinf(hb);
  const float cg = cosf(hg), sg = sinf(hg);
  const float m00r = cb*ca, m00i =  sb*sa;
  const float m01r = -sb*ca, m01i = -cb*sa;
  const float m10r =  sb*ca, m10i = -cb*sa;
  const float m11r = cb*ca,  m11i = -sb*sa;
  gt[8*t+0] = cg*m00r + sg*m00i;  gt[8*t+1] = cg*m00i - sg*m00r;
  gt[8*t+2] = cg*m01r + sg*m01i;  gt[8*t+3] = cg*m01i - sg*m01r;
  gt[8*t+4] = cg*m10r - sg*m10i;  gt[8*t+5] = cg*m10i + sg*m10r;
  gt[8*t+6] = cg*m11r - sg*m11i;  gt[8*t+7] = cg*m11i + sg*m11r;
  gt[80+2*t] = cosf(hd); gt[81+2*t] = sinf(hd);
}

__global__ void __launch_bounds__(NT)   // NO waves-per-EU hint (R3/R6 spill lesson)
qqk_kernel(const float* __restrict__ x, const float* __restrict__ gt,
           float* __restrict__ out)
{
  __shared__ __align__(16) f2 smem[2048];   // one 1024-f2 state buffer per wave (2 waves)
  const int t = threadIdx.x, wave = t >> 6, lane = t & 63;
  f2* bb = smem + (wave << 10);
  const f2* g2  = (const f2*)gt;
  const f2* gry = (const f2*)(gt + 80);
  const size_t e = (size_t)blockIdx.x * 2 + wave;
  const float* xg = x + e * NFEAT;

  const int aA = (lane << 1) ^ ((lane >> 2) & 14);
  const int aB = ((lane >> 3) << 7) | ((lane & 7) << 1);
  const int aC = (lane << 4) ^ ((lane << 1) & 14);

  // twiddle constants T(e) = exp(+2pi i e/1024)
  const f2 T1c   = { 0.9999811752826011f, 0.0061358846491545f };
  const f2 T2c   = { 0.9999247018391445f, 0.0122715382857199f };
  const f2 T4c   = { 0.9996988186962042f, 0.0245412285229123f };
  const f2 T8c   = { 0.9987954562051724f, 0.0490676743274180f };
  const f2 T16c  = { 0.9951847266721969f, 0.0980171403295606f };
  const f2 T32c  = { 0.9807852804032304f, 0.1950903220161283f };
  const float c45 = 0.7071067811865476f, c22 = 0.9238795325112867f, s22 = 0.3826834323650898f;
  const f2 T64c  = { c22, s22 };
  const f2 T128c = { c45, c45 };

  f2 xrxi[10];
  f2 xv[16];
  // ---- P0: global float2 load + norm + gates q0,q1,q2 (bits 9,8,7) and q9 (bit 0); write A' ----
  float ss = 0.f;
  #pragma unroll
  for (int k = 0; k < 6; ++k){
    const float2 v = *(const float2*)(xg + (k << 7) + (lane << 1));
    xv[2*k] = f2{v.x, 0.f}; xv[2*k+1] = f2{v.y, 0.f};
    ss += v.x*v.x + v.y*v.y;
  }
  #pragma unroll
  for (int m = 12; m < 16; ++m) xv[m] = f2{0.f, 0.f};
  ss = dpp_add<0xB1>(ss); ss = dpp_add<0x4E>(ss);
  ss += __shfl_xor(ss, 4); ss += __shfl_xor(ss, 8); ss += __shfl_xor(ss, 16); ss += __shfl_xor(ss, 32);
  const float invn = 1.0f / fmaxf(sqrtf(ss), 1e-8f);
  #pragma unroll
  for (int m = 0; m < 12; ++m) xv[m].x *= invn;
  gate_on<8>(xv, g2+0); gate_on<4>(xv, g2+4); gate_on<2>(xv, g2+8); gate_on<1>(xv, g2+36);
  wrA(bb, aA, xv);
  MEMFENCE();
  // ---- P1: gates q3,q4,q5 (bits 6,5,4), layout B' ----
  rdB(bb, aB, xv);
  gate_on<8>(xv, g2+12); gate_on<4>(xv, g2+16); gate_on<2>(xv, g2+20);
  wrB(bb, aB, xv);
  MEMFENCE();
  // ---- P2: gates q6,q7,q8 (bits 3,2,1), layout C' ----
  rdC(bb, aC, xv);
  gate_on<8>(xv, g2+24); gate_on<4>(xv, g2+28); gate_on<2>(xv, g2+32);
  wrC(bb, aC, xv);
  MEMFENCE();
  // ---- P3: CNOT-ring gather (to C' slots) + RY q6,q7,q8,q9; write C' ----
  { const int ag = swz2(cnot_perm(lane << 4));
    #pragma unroll
    for (int m = 0; m < 16; ++m) xv[m] = bb[ag ^ swz2(cnot_perm(m))];
  }
  MEMFENCE();   // all gather reads precede the overwrites below (in-order DS)
  ry_on<8>(xv, gry[6]); ry_on<4>(xv, gry[7]); ry_on<2>(xv, gry[8]); ry_on<1>(xv, gry[9]);
  wrC(bb, aC, xv);
  MEMFENCE();
  // ---- P4: RY q3,q4,q5, layout B' ----
  rdB(bb, aB, xv);
  ry_on<8>(xv, gry[3]); ry_on<4>(xv, gry[4]); ry_on<2>(xv, gry[5]);
  wrB(bb, aB, xv);
  MEMFENCE();
  // ---- P5: RY q0,q1,q2 + FFT stages bits 9,8,7 + EXPECTATIONS q9,q8,q7 (layout A') ----
  // Remaining stages act on bits 6..0 only; each unnormalized bfly stage has
  // B^dag B = 2I, so a pairsum taken after 3 of 10 stages is missing 2^7.
  rdA(bb, aA, xv);
  ry_on<8>(xv, gry[0]); ry_on<4>(xv, gry[1]); ry_on<2>(xv, gry[2]);
  { float sa, ca; __sincosf((float)lane * 1.2271846303085130e-2f, &sa, &ca);  // BT = T(2*lane)
    const f2 BT = {ca, sa};
    const f2 BT2 = pk_cmul(BT, BT);
    const f2 BT4 = pk_cmul(BT2, BT2);
    f2 t9[8];
    t9[0] = BT;               t9[1] = pk_cmul(BT, T1c);
    t9[2] = pk_cmul(BT, T128c); t9[3] = pk_cmul(t9[1], T128c);
    t9[4] = rot90(t9[0]); t9[5] = rot90(t9[1]); t9[6] = rot90(t9[2]); t9[7] = rot90(t9[3]);
    #pragma unroll
    for (int m = 0; m < 8; ++m) bfly(xv[m], xv[m+8], t9[m]);        // stage bit 9
    f2 u[4];
    u[0] = BT2; u[1] = pk_cmul(BT2, T2c); u[2] = rot90(u[0]); u[3] = rot90(u[1]);
    #pragma unroll
    for (int m = 0; m < 16; ++m) if (!(m & 4)) bfly(xv[m], xv[m|4], u[m & 3]);   // bit 8
    f2 v2[2];
    v2[0] = BT4; v2[1] = pk_cmul(BT4, T4c);
    #pragma unroll
    for (int m = 0; m < 16; ++m) if (!(m & 2)) bfly(xv[m], xv[m|2], v2[m & 1]);  // bit 7
  }
  xrxi[9] = pairsum16<8>(xv) * 128.0f;   // missing 2^7 from remaining 7 stages
  xrxi[8] = pairsum16<4>(xv) * 128.0f;
  xrxi[7] = pairsum16<2>(xv) * 128.0f;
  wrA(bb, aA, xv);
  MEMFENCE();
  // ---- P6: FFT stages bits 6,5,4 + EXPECTATIONS q6,q5,q4 (layout B') ----
  rdB(bb, aB, xv);
  { float sa, ca; __sincosf((float)(lane & 7) * 9.8174770424681035e-2f, &sa, &ca);  // CT = T(16*lane_l)
    const f2 CT = {ca, sa};
    const f2 CT2 = pk_cmul(CT, CT);
    const f2 CT4 = pk_cmul(CT2, CT2);
    f2 t6[8];
    t6[0] = CT;               t6[1] = pk_cmul(CT, T8c);
    t6[2] = pk_cmul(CT, T128c); t6[3] = pk_cmul(t6[1], T128c);
    t6[4] = rot90(t6[0]); t6[5] = rot90(t6[1]); t6[6] = rot90(t6[2]); t6[7] = rot90(t6[3]);
    #pragma unroll
    for (int m = 0; m < 8; ++m) bfly(xv[m], xv[m+8], t6[m]);        // stage bit 6
    f2 u[4];
    u[0] = CT2; u[1] = pk_cmul(CT2, T16c); u[2] = rot90(u[0]); u[3] = rot90(u[1]);
    #pragma unroll
    for (int m = 0; m < 16; ++m) if (!(m & 4)) bfly(xv[m], xv[m|4], u[m & 3]);   // bit 5
    f2 v2[2];
    v2[0] = CT4; v2[1] = pk_cmul(CT4, T32c);
    #pragma unroll
    for (int m = 0; m < 16; ++m) if (!(m & 2)) bfly(xv[m], xv[m|2], v2[m & 1]);  // bit 4
  }
  xrxi[6] = pairsum16<8>(xv) * 16.0f;    // missing 2^4 from remaining 4 stages
  xrxi[5] = pairsum16<4>(xv) * 16.0f;
  xrxi[4] = pairsum16<2>(xv) * 16.0f;
  wrB(bb, aB, xv);
  MEMFENCE();
  // ---- P7: FFT stages bits 3,2,1,0 + expectations q0..q3 + probabilities (layout C', NO write-back) ----
  rdC(bb, aC, xv);
  // stage bit 3: tw = T(64*m)
  bfly1(xv[0], xv[8]);
  bfly (xv[1], xv[9],  T64c);
  bfly (xv[2], xv[10], T128c);
  bfly (xv[3], xv[11], f2{ s22, c22});
  bflyI(xv[4], xv[12]);
  bfly (xv[5], xv[13], f2{-s22, c22});
  bfly (xv[6], xv[14], f2{-c45, c45});
  bfly (xv[7], xv[15], f2{-c22, s22});
  // stage bit 2: tw = T(128*(m&3))
  #pragma unroll
  for (int m = 0; m < 16; ++m) if (!(m & 4)){
    const int s = m & 3;
    if      (s == 0) bfly1(xv[m], xv[m|4]);
    else if (s == 1) bfly (xv[m], xv[m|4], T128c);
    else if (s == 2) bflyI(xv[m], xv[m|4]);
    else             bfly (xv[m], xv[m|4], f2{-c45, c45});
  }
  // stage bit 1: tw = {1, i}
  #pragma unroll
  for (int m = 0; m < 16; ++m) if (!(m & 2)){
    if (m & 1) bflyI(xv[m], xv[m|2]); else bfly1(xv[m], xv[m|2]);
  }
  // stage bit 0: tw = 1
  #pragma unroll
  for (int m = 0; m < 16; m += 2) bfly1(xv[m], xv[m+1]);
  xrxi[0] = pairsum16<1>(xv); xrxi[1] = pairsum16<2>(xv);
  xrxi[2] = pairsum16<4>(xv); xrxi[3] = pairsum16<8>(xv);
  float S = 0.f, z0 = 0.f, z1 = 0.f, z2 = 0.f, z3 = 0.f;
  #pragma unroll
  for (int m = 0; m < 16; ++m){
    const f2 q = pk_mul2(xv[m], xv[m]); const float n = q.x + q.y;
    S += n;
    z0 += (m & 1) ? -n : n;  z1 += (m & 2) ? -n : n;
    z2 += (m & 4) ? -n : n;  z3 += (m & 8) ? -n : n;
  }
  MEMFENCE();   // all state reads precede the reduction-row overwrite

  // ---- Walsh-Hadamard over lane bits on S -> Z4..Z9 ----
  float d0, d1, d2, d3, d4, d5;
  { float s = S, wv;
    wv = dpp_mov<0xB1>(s); d0 = (lane & 1)  ? (wv - s) : (s - wv); s += wv;
    wv = dpp_mov<0x4E>(s); d1 = (lane & 2)  ? (wv - s) : (s - wv); s += wv;
    wv = __shfl_xor(s, 4);  d2 = (lane & 4)  ? (wv - s) : (s - wv); s += wv;
    wv = __shfl_xor(s, 8);  d3 = (lane & 8)  ? (wv - s) : (s - wv); s += wv;
    wv = __shfl_xor(s, 16); d4 = (lane & 16) ? (wv - s) : (s - wv); s += wv;
    wv = __shfl_xor(s, 32); d5 = (lane & 32) ? (wv - s) : (s - wv); s += wv;
    d0 = dpp_add<0x4E>(d0); d0 += __shfl_xor(d0, 4); d0 += __shfl_xor(d0, 8); d0 += __shfl_xor(d0, 16); d0 += __shfl_xor(d0, 32);
    d1 += __shfl_xor(d1, 4); d1 += __shfl_xor(d1, 8); d1 += __shfl_xor(d1, 16); d1 += __shfl_xor(d1, 32);
    d2 += __shfl_xor(d2, 8); d2 += __shfl_xor(d2, 16); d2 += __shfl_xor(d2, 32);
    d3 += __shfl_xor(d3, 16); d3 += __shfl_xor(d3, 32);
    d4 += __shfl_xor(d4, 32);
  }

  // ---- quad pre-sum via DPP, then 24x17-stride float row transpose (conflict-free) ----
  #pragma unroll
  for (int q = 0; q < 10; ++q){
    xrxi[q].x = dpp_add<0x4E>(dpp_add<0xB1>(xrxi[q].x));
    xrxi[q].y = dpp_add<0x4E>(dpp_add<0xB1>(xrxi[q].y));
  }
  z0 = dpp_add<0x4E>(dpp_add<0xB1>(z0));
  z1 = dpp_add<0x4E>(dpp_add<0xB1>(z1));
  z2 = dpp_add<0x4E>(dpp_add<0xB1>(z2));
  z3 = dpp_add<0x4E>(dpp_add<0xB1>(z3));
  float* rb = (float*)bb;
  const int g = lane >> 2;
  if ((lane & 3) == 0){
    #pragma unroll
    for (int q = 0; q < 10; ++q){ rb[q*17 + g] = xrxi[q].x; rb[(10+q)*17 + g] = xrxi[q].y; }
    rb[20*17 + g] = z0; rb[21*17 + g] = z1; rb[22*17 + g] = z2; rb[23*17 + g] = z3;
  }
  MEMFENCE();   // row writes precede row reads (same-wave in-order DS)
  float* ob = out + e * 30;
  if (lane < 24){
    float acc = 0.f;
    #pragma unroll
    for (int gg = 0; gg < 16; ++gg) acc += rb[lane*17 + gg];
    ob[lane] = acc * ((lane < 20) ? (2.0f/1024.0f) : (1.0f/1024.0f));
  }
  if (lane == 0){
    const float zs = 1.0f/1024.0f;
    ob[24] = d0*zs; ob[25] = d1*zs; ob[26] = d2*zs;
    ob[27] = d3*zs; ob[28] = d4*zs; ob[29] = d5*zs;
  }
}

extern "C" void kernel_launch(void* const* d_in, const int* in_sizes, int n_in,
                              void* d_out, int out_size, void* d_ws, size_t ws_size,
                              hipStream_t stream) {
  const float* x = (const float*)d_in[0];
  const float* w = (const float*)d_in[1];
  float* out = (float*)d_out;
  float* gt  = (float*)d_ws;           // 100 floats of gate tables
  const int B = in_sizes[0] / NFEAT;   // 8192
  gate_prep<<<1, 16, 0, stream>>>(w, gt);
  qqk_kernel<<<B/2, NT, 0, stream>>>(x, gt, out);
}

// Round 14
// 46.303 us; speedup vs baseline: 1.0095x; 1.0095x over previous
//
#include <hip/hip_runtime.h>
#include <math.h>

#define NFEAT 768
#define NT    128   // 2 waves/block, 1 wave = 1 element, ZERO barriers

typedef float f2 __attribute__((ext_vector_type(2)));
#define MEMFENCE() asm volatile("" ::: "memory")

// bit0-preserving GF2-linear swizzle: addr bits 3..1 ^= index bits 6..4.
__device__ __forceinline__ int swz2(int j){ return j ^ ((j >> 3) & 0xE); }

// Composite of the CNOT ring CNOT(0,1),...,CNOT(9,0): s_after[j] = s_before[perm(j)]. GF2-linear.
__device__ __forceinline__ int cnot_perm(int j){
  int i = j;
  i ^= ((i >> 0) & 1) << 9;
  i ^= ((i >> 1) & 1) << 0;
  i ^= ((i >> 2) & 1) << 1;
  i ^= ((i >> 3) & 1) << 2;
  i ^= ((i >> 4) & 1) << 3;
  i ^= ((i >> 5) & 1) << 4;
  i ^= ((i >> 6) & 1) << 5;
  i ^= ((i >> 7) & 1) << 6;
  i ^= ((i >> 8) & 1) << 7;
  i ^= ((i >> 9) & 1) << 8;
  return i;
}

// ---- DPP cross-lane (VALU pipe): quad_perm xor1=0xB1, xor2=0x4E ----
template<int CTRL>
__device__ __forceinline__ float dpp_mov(float x){
  return __builtin_bit_cast(float,
    __builtin_amdgcn_update_dpp(0, __builtin_bit_cast(int, x), CTRL, 0xF, 0xF, true));
}
template<int CTRL>
__device__ __forceinline__ float dpp_add(float x){ return x + dpp_mov<CTRL>(x); }

// ---- packed-f32 primitives (VOP3P) ----
__device__ __forceinline__ f2 pk_add(f2 a, f2 b){
  f2 d; asm("v_pk_add_f32 %0, %1, %2" : "=v"(d) : "v"(a), "v"(b)); return d;
}
__device__ __forceinline__ f2 pk_sub(f2 a, f2 b){
  f2 d; asm("v_pk_add_f32 %0, %1, %2 neg_lo:[0,1] neg_hi:[0,1]" : "=v"(d) : "v"(a), "v"(b)); return d;
}
__device__ __forceinline__ f2 pk_mul2(f2 a, f2 b){
  f2 d; asm("v_pk_mul_f32 %0, %1, %2" : "=v"(d) : "v"(a), "v"(b)); return d;
}
__device__ __forceinline__ f2 pk_fma2(f2 a, f2 b, f2 c){
  f2 d; asm("v_pk_fma_f32 %0, %1, %2, %3" : "=v"(d) : "v"(a), "v"(b), "v"(c)); return d;
}
__device__ __forceinline__ f2 pk_cmul(f2 s, f2 v){
  f2 d;
  asm("v_pk_mul_f32 %0, %1, %2 op_sel:[0,0] op_sel_hi:[0,1]\n\t"
      "v_pk_fma_f32 %0, %1, %2, %0 op_sel:[1,1,0] op_sel_hi:[1,0,1] neg_lo:[0,1,0]"
      : "=&v"(d) : "v"(s), "v"(v));
  return d;
}
__device__ __forceinline__ f2 pk_cfma(f2 s, f2 v, f2 acc){
  f2 d;
  asm("v_pk_fma_f32 %0, %2, %3, %1 op_sel:[0,0,0] op_sel_hi:[0,1,1]\n\t"
      "v_pk_fma_f32 %0, %2, %3, %0 op_sel:[1,1,0] op_sel_hi:[1,0,1] neg_lo:[0,1,0]"
      : "=&v"(d) : "v"(acc), "v"(s), "v"(v));
  return d;
}
// d = acc + (a.r*b.i, -a.i*b.r)
__device__ __forceinline__ f2 pk_cross(f2 a, f2 b, f2 acc){
  f2 d;
  asm("v_pk_fma_f32 %0, %2, %3, %1 op_sel:[0,1,0] op_sel_hi:[1,0,1] neg_hi:[1,0,0]"
      : "=&v"(d) : "v"(acc), "v"(a), "v"(b));
  return d;
}
__device__ __forceinline__ void pk_ry(f2 cs, f2& a, f2& b){
  f2 t1, t2, na, nb;
  asm("v_pk_mul_f32 %0, %2, %3 op_sel:[1,0] op_sel_hi:[1,1] neg_lo:[1,0] neg_hi:[1,0]\n\t"
      "v_pk_mul_f32 %1, %2, %4 op_sel:[1,0] op_sel_hi:[1,1]"
      : "=&v"(t1), "=&v"(t2) : "v"(cs), "v"(b), "v"(a));
  asm("v_pk_fma_f32 %0, %2, %3, %4 op_sel:[0,0,0] op_sel_hi:[0,1,1]\n\t"
      "v_pk_fma_f32 %1, %2, %5, %6 op_sel:[0,0,0] op_sel_hi:[0,1,1]"
      : "=&v"(na), "=&v"(nb) : "v"(cs), "v"(a), "v"(t1), "v"(b), "v"(t2));
  a = na; b = nb;
}
__device__ __forceinline__ void gateU(const f2* g, f2& a, f2& b){
  const f2 na = pk_cfma(g[1], b, pk_cmul(g[0], a));
  const f2 nb = pk_cfma(g[3], b, pk_cmul(g[2], a));
  a = na; b = nb;
}
__device__ __forceinline__ f2 rot90(f2 v){ return f2{-v.y, v.x}; }
__device__ __forceinline__ void bfly(f2& a, f2& b, f2 tw){
  const f2 u = pk_add(a, b), v = pk_sub(a, b);
  a = u; b = pk_cmul(tw, v);
}
__device__ __forceinline__ void bfly1(f2& a, f2& b){
  const f2 u = pk_add(a, b), v = pk_sub(a, b); a = u; b = v;
}
__device__ __forceinline__ void bflyI(f2& a, f2& b){
  const f2 u = pk_add(a, b), v = pk_sub(a, b); a = u; b = f2{-v.y, v.x};
}

template<int MASK>
__device__ __forceinline__ void gate_on(f2* xv, const f2* g){
  #pragma unroll
  for (int m = 0; m < 16; ++m) if (!(m & MASK)) gateU(g, xv[m], xv[m|MASK]);
}
template<int MASK>
__device__ __forceinline__ void ry_on(f2* xv, const f2 cs){
  #pragma unroll
  for (int m = 0; m < 16; ++m) if (!(m & MASK)) pk_ry(cs, xv[m], xv[m|MASK]);
}
template<int MASK>
__device__ __forceinline__ f2 pairsum16(const f2* z){
  f2 rp = {0.f, 0.f}, ip = {0.f, 0.f};
  #pragma unroll
  for (int m = 0; m < 16; ++m) if (!(m & MASK)){
    rp = pk_fma2(z[m], z[m|MASK], rp);
    ip = pk_cross(z[m], z[m|MASK], ip);
  }
  return f2{ rp.x + rp.y, ip.x + ip.y };
}

// ---- b128-paired LDS I/O (layouts A'/B'/C' as in R10/R12) ----
__device__ __forceinline__ void rdA(const f2* bb, int a0, f2* xv){
  #pragma unroll
  for (int k = 0; k < 8; ++k){
    const float4 v = *(const float4*)(bb + (a0 ^ (k << 7)));
    xv[2*k] = f2{v.x, v.y}; xv[2*k+1] = f2{v.z, v.w};
  }
}
__device__ __forceinline__ void wrA(f2* bb, int a0, const f2* xv){
  #pragma unroll
  for (int k = 0; k < 8; ++k)
    *(float4*)(bb + (a0 ^ (k << 7))) = make_float4(xv[2*k].x, xv[2*k].y, xv[2*k+1].x, xv[2*k+1].y);
}
__device__ __forceinline__ void rdB(const f2* bb, int a0, f2* xv){
  #pragma unroll
  for (int k = 0; k < 8; ++k){
    const float4 v = *(const float4*)(bb + (a0 ^ ((k << 4) | (k << 1))));
    xv[2*k] = f2{v.x, v.y}; xv[2*k+1] = f2{v.z, v.w};
  }
}
__device__ __forceinline__ void wrB(f2* bb, int a0, const f2* xv){
  #pragma unroll
  for (int k = 0; k < 8; ++k)
    *(float4*)(bb + (a0 ^ ((k << 4) | (k << 1)))) = make_float4(xv[2*k].x, xv[2*k].y, xv[2*k+1].x, xv[2*k+1].y);
}
__device__ __forceinline__ void rdC(const f2* bb, int a0, f2* xv){
  #pragma unroll
  for (int k = 0; k < 8; ++k){
    const float4 v = *(const float4*)(bb + (a0 ^ (k << 1)));
    xv[2*k] = f2{v.x, v.y}; xv[2*k+1] = f2{v.z, v.w};
  }
}
__device__ __forceinline__ void wrC(f2* bb, int a0, const f2* xv){
  #pragma unroll
  for (int k = 0; k < 8; ++k)
    *(float4*)(bb + (a0 ^ (k << 1))) = make_float4(xv[2*k].x, xv[2*k].y, xv[2*k+1].x, xv[2*k+1].y);
}

__global__ void gate_prep(const float* __restrict__ w, float* __restrict__ gt){
  const int t = threadIdx.x;
  if (t >= 10) return;
  const float ha = 0.5f*w[t*4+0], hb = 0.5f*w[t*4+1];
  const float hg = 0.5f*w[t*4+2], hd = 0.5f*w[t*4+3];
  const float ca = cosf(ha), sa = sinf(ha);
  const float cb = cosf(hb), sb = sinf(hb);
  const float cg = cosf(hg), sg = sinf(hg);
  const float m00r = cb*ca, m00i =  sb*sa;
  const float m01r = -sb*ca, m01i = -cb*sa;
  const float m10r =  sb*ca, m10i = -cb*sa;
  const float m11r = cb*ca,  m11i = -sb*sa;
  gt[8*t+0] = cg*m00r + sg*m00i;  gt[8*t+1] = cg*m00i - sg*m00r;
  gt[8*t+2] = cg*m01r + sg*m01i;  gt[8*t+3] = cg*m01i - sg*m01r;
  gt[8*t+4] = cg*m10r - sg*m10i;  gt[8*t+5] = cg*m10i + sg*m10r;
  gt[8*t+6] = cg*m11r - sg*m11i;  gt[8*t+7] = cg*m11i + sg*m11r;
  gt[80+2*t] = cosf(hd); gt[81+2*t] = sinf(hd);
}

__global__ void __launch_bounds__(NT, 4)   // VGPR cap 128: room for addr-cache + chain ILP, far above ~80 live
qqk_kernel(const float* __restrict__ x, const float* __restrict__ gt,
           float* __restrict__ out)
{
  __shared__ __align__(16) f2 smem[2048];   // one 1024-f2 state buffer per wave (2 waves)
  const int t = threadIdx.x, wave = t >> 6, lane = t & 63;
  f2* bb = smem + (wave << 10);
  const f2* g2  = (const f2*)gt;
  const f2* gry = (const f2*)(gt + 80);
  const size_t e = (size_t)blockIdx.x * 2 + wave;
  const float* xg = x + e * NFEAT;

  const int aA = (lane << 1) ^ ((lane >> 2) & 14);
  const int aB = ((lane >> 3) << 7) | ((lane & 7) << 1);
  const int aC = (lane << 4) ^ ((lane << 1) & 14);

  // twiddle constants T(e) = exp(+2pi i e/1024)
  const f2 T1c   = { 0.9999811752826011f, 0.0061358846491545f };
  const f2 T2c   = { 0.9999247018391445f, 0.0122715382857199f };
  const f2 T4c   = { 0.9996988186962042f, 0.0245412285229123f };
  const f2 T8c   = { 0.9987954562051724f, 0.0490676743274180f };
  const f2 T16c  = { 0.9951847266721969f, 0.0980171403295606f };
  const f2 T32c  = { 0.9807852804032304f, 0.1950903220161283f };
  const float c45 = 0.7071067811865476f, c22 = 0.9238795325112867f, s22 = 0.3826834323650898f;
  const f2 T64c  = { c22, s22 };
  const f2 T128c = { c45, c45 };

  f2 xrxi[10];
  f2 xv[16];
  // ---- P0: global float2 load + norm + gates q0,q1,q2 (bits 9,8,7) and q9 (bit 0); write A' ----
  float ss = 0.f;
  #pragma unroll
  for (int k = 0; k < 6; ++k){
    const float2 v = *(const float2*)(xg + (k << 7) + (lane << 1));
    xv[2*k] = f2{v.x, 0.f}; xv[2*k+1] = f2{v.y, 0.f};
    ss += v.x*v.x + v.y*v.y;
  }
  #pragma unroll
  for (int m = 12; m < 16; ++m) xv[m] = f2{0.f, 0.f};
  ss = dpp_add<0xB1>(ss); ss = dpp_add<0x4E>(ss);
  ss += __shfl_xor(ss, 4); ss += __shfl_xor(ss, 8); ss += __shfl_xor(ss, 16); ss += __shfl_xor(ss, 32);
  const float invn = 1.0f / fmaxf(sqrtf(ss), 1e-8f);
  #pragma unroll
  for (int m = 0; m < 12; ++m) xv[m].x *= invn;
  gate_on<8>(xv, g2+0); gate_on<4>(xv, g2+4); gate_on<2>(xv, g2+8); gate_on<1>(xv, g2+36);
  wrA(bb, aA, xv);
  MEMFENCE();
  // ---- P1: gates q3,q4,q5 (bits 6,5,4), layout B' ----
  rdB(bb, aB, xv);
  gate_on<8>(xv, g2+12); gate_on<4>(xv, g2+16); gate_on<2>(xv, g2+20);
  wrB(bb, aB, xv);
  MEMFENCE();
  // ---- P2: gates q6,q7,q8 (bits 3,2,1), layout C' ----
  rdC(bb, aC, xv);
  gate_on<8>(xv, g2+24); gate_on<4>(xv, g2+28); gate_on<2>(xv, g2+32);
  wrC(bb, aC, xv);
  MEMFENCE();
  // ---- P3: CNOT-ring gather (to C' slots) + RY q6,q7,q8,q9; write C' ----
  { const int ag = swz2(cnot_perm(lane << 4));
    #pragma unroll
    for (int m = 0; m < 16; ++m) xv[m] = bb[ag ^ swz2(cnot_perm(m))];
  }
  MEMFENCE();   // all gather reads precede the overwrites below (in-order DS)
  ry_on<8>(xv, gry[6]); ry_on<4>(xv, gry[7]); ry_on<2>(xv, gry[8]); ry_on<1>(xv, gry[9]);
  wrC(bb, aC, xv);
  MEMFENCE();
  // ---- P4: RY q0,q1,q2 + FFT stages bits 9,8,7 + EXPECTATIONS q9,q8,q7 (layout A') ----
  // RY q3,q4,q5 (bits 6,5,4) commutes with these stages -> deferred to P5 (saves a B' roundtrip).
  // Each unnormalized bfly stage has B^dag B = 2I; pairsum after 3 of 10 stages is missing 2^7.
  rdA(bb, aA, xv);
  ry_on<8>(xv, gry[0]); ry_on<4>(xv, gry[1]); ry_on<2>(xv, gry[2]);
  { float sa, ca; __sincosf((float)lane * 1.2271846303085130e-2f, &sa, &ca);  // BT = T(2*lane)
    const f2 BT = {ca, sa};
    const f2 BT2 = pk_cmul(BT, BT);
    const f2 BT4 = pk_cmul(BT2, BT2);
    f2 t9[8];
    t9[0] = BT;               t9[1] = pk_cmul(BT, T1c);
    t9[2] = pk_cmul(BT, T128c); t9[3] = pk_cmul(t9[1], T128c);
    t9[4] = rot90(t9[0]); t9[5] = rot90(t9[1]); t9[6] = rot90(t9[2]); t9[7] = rot90(t9[3]);
    #pragma unroll
    for (int m = 0; m < 8; ++m) bfly(xv[m], xv[m+8], t9[m]);        // stage bit 9
    f2 u[4];
    u[0] = BT2; u[1] = pk_cmul(BT2, T2c); u[2] = rot90(u[0]); u[3] = rot90(u[1]);
    #pragma unroll
    for (int m = 0; m < 16; ++m) if (!(m & 4)) bfly(xv[m], xv[m|4], u[m & 3]);   // bit 8
    f2 v2[2];
    v2[0] = BT4; v2[1] = pk_cmul(BT4, T4c);
    #pragma unroll
    for (int m = 0; m < 16; ++m) if (!(m & 2)) bfly(xv[m], xv[m|2], v2[m & 1]);  // bit 7
  }
  xrxi[9] = pairsum16<8>(xv) * 128.0f;   // missing 2^7 from remaining 7 stages
  xrxi[8] = pairsum16<4>(xv) * 128.0f;
  xrxi[7] = pairsum16<2>(xv) * 128.0f;
  wrA(bb, aA, xv);
  MEMFENCE();
  // ---- P5: RY q3,q4,q5 + FFT stages bits 6,5,4 + EXPECTATIONS q6,q5,q4 (layout B') ----
  rdB(bb, aB, xv);
  ry_on<8>(xv, gry[3]); ry_on<4>(xv, gry[4]); ry_on<2>(xv, gry[5]);
  { float sa, ca; __sincosf((float)(lane & 7) * 9.8174770424681035e-2f, &sa, &ca);  // CT = T(16*lane_l)
    const f2 CT = {ca, sa};
    const f2 CT2 = pk_cmul(CT, CT);
    const f2 CT4 = pk_cmul(CT2, CT2);
    f2 t6[8];
    t6[0] = CT;               t6[1] = pk_cmul(CT, T8c);
    t6[2] = pk_cmul(CT, T128c); t6[3] = pk_cmul(t6[1], T128c);
    t6[4] = rot90(t6[0]); t6[5] = rot90(t6[1]); t6[6] = rot90(t6[2]); t6[7] = rot90(t6[3]);
    #pragma unroll
    for (int m = 0; m < 8; ++m) bfly(xv[m], xv[m+8], t6[m]);        // stage bit 6
    f2 u[4];
    u[0] = CT2; u[1] = pk_cmul(CT2, T16c); u[2] = rot90(u[0]); u[3] = rot90(u[1]);
    #pragma unroll
    for (int m = 0; m < 16; ++m) if (!(m & 4)) bfly(xv[m], xv[m|4], u[m & 3]);   // bit 5
    f2 v2[2];
    v2[0] = CT4; v2[1] = pk_cmul(CT4, T32c);
    #pragma unroll
    for (int m = 0; m < 16; ++m) if (!(m & 2)) bfly(xv[m], xv[m|2], v2[m & 1]);  // bit 4
  }
  xrxi[6] = pairsum16<8>(xv) * 16.0f;    // missing 2^4 from remaining 4 stages
  xrxi[5] = pairsum16<4>(xv) * 16.0f;
  xrxi[4] = pairsum16<2>(xv) * 16.0f;
  wrB(bb, aB, xv);
  MEMFENCE();
  // ---- P6: FFT stages bits 3,2,1,0 + expectations q0..q3 + probabilities (layout C', NO write-back) ----
  rdC(bb, aC, xv);
  // stage bit 3: tw = T(64*m)
  bfly1(xv[0], xv[8]);
  bfly (xv[1], xv[9],  T64c);
  bfly (xv[2], xv[10], T128c);
  bfly (xv[3], xv[11], f2{ s22, c22});
  bflyI(xv[4], xv[12]);
  bfly (xv[5], xv[13], f2{-s22, c22});
  bfly (xv[6], xv[14], f2{-c45, c45});
  bfly (xv[7], xv[15], f2{-c22, s22});
  // stage bit 2: tw = T(128*(m&3))
  #pragma unroll
  for (int m = 0; m < 16; ++m) if (!(m & 4)){
    const int s = m & 3;
    if      (s == 0) bfly1(xv[m], xv[m|4]);
    else if (s == 1) bfly (xv[m], xv[m|4], T128c);
    else if (s == 2) bflyI(xv[m], xv[m|4]);
    else             bfly (xv[m], xv[m|4], f2{-c45, c45});
  }
  // stage bit 1: tw = {1, i}
  #pragma unroll
  for (int m = 0; m < 16; ++m) if (!(m & 2)){
    if (m & 1) bflyI(xv[m], xv[m|2]); else bfly1(xv[m], xv[m|2]);
  }
  // stage bit 0: tw = 1
  #pragma unroll
  for (int m = 0; m < 16; m += 2) bfly1(xv[m], xv[m+1]);
  xrxi[0] = pairsum16<1>(xv); xrxi[1] = pairsum16<2>(xv);
  xrxi[2] = pairsum16<4>(xv); xrxi[3] = pairsum16<8>(xv);
  float S = 0.f, z0 = 0.f, z1 = 0.f, z2 = 0.f, z3 = 0.f;
  #pragma unroll
  for (int m = 0; m < 16; ++m){
    const f2 q = pk_mul2(xv[m], xv[m]); const float n = q.x + q.y;
    S += n;
    z0 += (m & 1) ? -n : n;  z1 += (m & 2) ? -n : n;
    z2 += (m & 4) ? -n : n;  z3 += (m & 8) ? -n : n;
  }
  MEMFENCE();   // all state reads precede the reduction-row overwrite

  // ---- Walsh-Hadamard over lane bits on S -> Z4..Z9 ----
  float d0, d1, d2, d3, d4, d5;
  { float s = S, wv;
    wv = dpp_mov<0xB1>(s); d0 = (lane & 1)  ? (wv - s) : (s - wv); s += wv;
    wv = dpp_mov<0x4E>(s); d1 = (lane & 2)  ? (wv - s) : (s - wv); s += wv;
    wv = __shfl_xor(s, 4);  d2 = (lane & 4)  ? (wv - s) : (s - wv); s += wv;
    wv = __shfl_xor(s, 8);  d3 = (lane & 8)  ? (wv - s) : (s - wv); s += wv;
    wv = __shfl_xor(s, 16); d4 = (lane & 16) ? (wv - s) : (s - wv); s += wv;
    wv = __shfl_xor(s, 32); d5 = (lane & 32) ? (wv - s) : (s - wv); s += wv;
    d0 = dpp_add<0x4E>(d0); d0 += __shfl_xor(d0, 4); d0 += __shfl_xor(d0, 8); d0 += __shfl_xor(d0, 16); d0 += __shfl_xor(d0, 32);
    d1 += __shfl_xor(d1, 4); d1 += __shfl_xor(d1, 8); d1 += __shfl_xor(d1, 16); d1 += __shfl_xor(d1, 32);
    d2 += __shfl_xor(d2, 8); d2 += __shfl_xor(d2, 16); d2 += __shfl_xor(d2, 32);
    d3 += __shfl_xor(d3, 16); d3 += __shfl_xor(d3, 32);
    d4 += __shfl_xor(d4, 32);
  }

  // ---- quad pre-sum via DPP, then 24x17-stride float row transpose (conflict-free) ----
  #pragma unroll
  for (int q = 0; q < 10; ++q){
    xrxi[q].x = dpp_add<0x4E>(dpp_add<0xB1>(xrxi[q].x));
    xrxi[q].y = dpp_add<0x4E>(dpp_add<0xB1>(xrxi[q].y));
  }
  z0 = dpp_add<0x4E>(dpp_add<0xB1>(z0));
  z1 = dpp_add<0x4E>(dpp_add<0xB1>(z1));
  z2 = dpp_add<0x4E>(dpp_add<0xB1>(z2));
  z3 = dpp_add<0x4E>(dpp_add<0xB1>(z3));
  float* rb = (float*)bb;
  const int g = lane >> 2;
  if ((lane & 3) == 0){
    #pragma unroll
    for (int q = 0; q < 10; ++q){ rb[q*17 + g] = xrxi[q].x; rb[(10+q)*17 + g] = xrxi[q].y; }
    rb[20*17 + g] = z0; rb[21*17 + g] = z1; rb[22*17 + g] = z2; rb[23*17 + g] = z3;
  }
  MEMFENCE();   // row writes precede row reads (same-wave in-order DS)
  float* ob = out + e * 30;
  if (lane < 24){
    float acc = 0.f;
    #pragma unroll
    for (int gg = 0; gg < 16; ++gg) acc += rb[lane*17 + gg];
    ob[lane] = acc * ((lane < 20) ? (2.0f/1024.0f) : (1.0f/1024.0f));
  }
  if (lane == 0){
    const float zs = 1.0f/1024.0f;
    ob[24] = d0*zs; ob[25] = d1*zs; ob[26] = d2*zs;
    ob[27] = d3*zs; ob[28] = d4*zs; ob[29] = d5*zs;
  }
}

extern "C" void kernel_launch(void* const* d_in, const int* in_sizes, int n_in,
                              void* d_out, int out_size, void* d_ws, size_t ws_size,
                              hipStream_t stream) {
  const float* x = (const float*)d_in[0];
  const float* w = (const float*)d_in[1];
  float* out = (float*)d_out;
  float* gt  = (float*)d_ws;           // 100 floats of gate tables
  const int B = in_sizes[0] / NFEAT;   // 8192
  gate_prep<<<1, 16, 0, stream>>>(w, gt);
  qqk_kernel<<<B/2, NT, 0, stream>>>(x, gt, out);
}

// Round 15
// 45.667 us; speedup vs baseline: 1.0235x; 1.0139x over previous
//
#include <hip/hip_runtime.h>
#include <math.h>

#define NFEAT 768
#define NT    64    // ONE wave = ONE element per block; 8KB LDS -> max resident waves probe

typedef float f2 __attribute__((ext_vector_type(2)));
#define MEMFENCE() asm volatile("" ::: "memory")

// bit0-preserving GF2-linear swizzle: addr bits 3..1 ^= index bits 6..4.
__device__ __forceinline__ int swz2(int j){ return j ^ ((j >> 3) & 0xE); }

// Composite of the CNOT ring CNOT(0,1),...,CNOT(9,0): s_after[j] = s_before[perm(j)]. GF2-linear.
__device__ __forceinline__ int cnot_perm(int j){
  int i = j;
  i ^= ((i >> 0) & 1) << 9;
  i ^= ((i >> 1) & 1) << 0;
  i ^= ((i >> 2) & 1) << 1;
  i ^= ((i >> 3) & 1) << 2;
  i ^= ((i >> 4) & 1) << 3;
  i ^= ((i >> 5) & 1) << 4;
  i ^= ((i >> 6) & 1) << 5;
  i ^= ((i >> 7) & 1) << 6;
  i ^= ((i >> 8) & 1) << 7;
  i ^= ((i >> 9) & 1) << 8;
  return i;
}

// ---- DPP cross-lane (VALU pipe): quad_perm xor1=0xB1, xor2=0x4E ----
template<int CTRL>
__device__ __forceinline__ float dpp_mov(float x){
  return __builtin_bit_cast(float,
    __builtin_amdgcn_update_dpp(0, __builtin_bit_cast(int, x), CTRL, 0xF, 0xF, true));
}
template<int CTRL>
__device__ __forceinline__ float dpp_add(float x){ return x + dpp_mov<CTRL>(x); }

// ---- packed-f32 primitives (VOP3P) ----
__device__ __forceinline__ f2 pk_add(f2 a, f2 b){
  f2 d; asm("v_pk_add_f32 %0, %1, %2" : "=v"(d) : "v"(a), "v"(b)); return d;
}
__device__ __forceinline__ f2 pk_sub(f2 a, f2 b){
  f2 d; asm("v_pk_add_f32 %0, %1, %2 neg_lo:[0,1] neg_hi:[0,1]" : "=v"(d) : "v"(a), "v"(b)); return d;
}
__device__ __forceinline__ f2 pk_mul2(f2 a, f2 b){
  f2 d; asm("v_pk_mul_f32 %0, %1, %2" : "=v"(d) : "v"(a), "v"(b)); return d;
}
__device__ __forceinline__ f2 pk_fma2(f2 a, f2 b, f2 c){
  f2 d; asm("v_pk_fma_f32 %0, %1, %2, %3" : "=v"(d) : "v"(a), "v"(b), "v"(c)); return d;
}
__device__ __forceinline__ f2 pk_cmul(f2 s, f2 v){
  f2 d;
  asm("v_pk_mul_f32 %0, %1, %2 op_sel:[0,0] op_sel_hi:[0,1]\n\t"
      "v_pk_fma_f32 %0, %1, %2, %0 op_sel:[1,1,0] op_sel_hi:[1,0,1] neg_lo:[0,1,0]"
      : "=&v"(d) : "v"(s), "v"(v));
  return d;
}
__device__ __forceinline__ f2 pk_cfma(f2 s, f2 v, f2 acc){
  f2 d;
  asm("v_pk_fma_f32 %0, %2, %3, %1 op_sel:[0,0,0] op_sel_hi:[0,1,1]\n\t"
      "v_pk_fma_f32 %0, %2, %3, %0 op_sel:[1,1,0] op_sel_hi:[1,0,1] neg_lo:[0,1,0]"
      : "=&v"(d) : "v"(acc), "v"(s), "v"(v));
  return d;
}
// d = acc + (a.r*b.i, -a.i*b.r)
__device__ __forceinline__ f2 pk_cross(f2 a, f2 b, f2 acc){
  f2 d;
  asm("v_pk_fma_f32 %0, %2, %3, %1 op_sel:[0,1,0] op_sel_hi:[1,0,1] neg_hi:[1,0,0]"
      : "=&v"(d) : "v"(acc), "v"(a), "v"(b));
  return d;
}
__device__ __forceinline__ void pk_ry(f2 cs, f2& a, f2& b){
  f2 t1, t2, na, nb;
  asm("v_pk_mul_f32 %0, %2, %3 op_sel:[1,0] op_sel_hi:[1,1] neg_lo:[1,0] neg_hi:[1,0]\n\t"
      "v_pk_mul_f32 %1, %2, %4 op_sel:[1,0] op_sel_hi:[1,1]"
      : "=&v"(t1), "=&v"(t2) : "v"(cs), "v"(b), "v"(a));
  asm("v_pk_fma_f32 %0, %2, %3, %4 op_sel:[0,0,0] op_sel_hi:[0,1,1]\n\t"
      "v_pk_fma_f32 %1, %2, %5, %6 op_sel:[0,0,0] op_sel_hi:[0,1,1]"
      : "=&v"(na), "=&v"(nb) : "v"(cs), "v"(a), "v"(t1), "v"(b), "v"(t2));
  a = na; b = nb;
}
__device__ __forceinline__ void gateU(const f2* g, f2& a, f2& b){
  const f2 na = pk_cfma(g[1], b, pk_cmul(g[0], a));
  const f2 nb = pk_cfma(g[3], b, pk_cmul(g[2], a));
  a = na; b = nb;
}
__device__ __forceinline__ f2 rot90(f2 v){ return f2{-v.y, v.x}; }
__device__ __forceinline__ void bfly(f2& a, f2& b, f2 tw){
  const f2 u = pk_add(a, b), v = pk_sub(a, b);
  a = u; b = pk_cmul(tw, v);
}
__device__ __forceinline__ void bfly1(f2& a, f2& b){
  const f2 u = pk_add(a, b), v = pk_sub(a, b); a = u; b = v;
}
__device__ __forceinline__ void bflyI(f2& a, f2& b){
  const f2 u = pk_add(a, b), v = pk_sub(a, b); a = u; b = f2{-v.y, v.x};
}

template<int MASK>
__device__ __forceinline__ void gate_on(f2* xv, const f2* g){
  #pragma unroll
  for (int m = 0; m < 16; ++m) if (!(m & MASK)) gateU(g, xv[m], xv[m|MASK]);
}
template<int MASK>
__device__ __forceinline__ void ry_on(f2* xv, const f2 cs){
  #pragma unroll
  for (int m = 0; m < 16; ++m) if (!(m & MASK)) pk_ry(cs, xv[m], xv[m|MASK]);
}
template<int MASK>
__device__ __forceinline__ f2 pairsum16(const f2* z){
  f2 rp = {0.f, 0.f}, ip = {0.f, 0.f};
  #pragma unroll
  for (int m = 0; m < 16; ++m) if (!(m & MASK)){
    rp = pk_fma2(z[m], z[m|MASK], rp);
    ip = pk_cross(z[m], z[m|MASK], ip);
  }
  return f2{ rp.x + rp.y, ip.x + ip.y };
}

// ---- b128-paired LDS I/O (layouts A'/B'/C' as in R10/R12) ----
__device__ __forceinline__ void rdA(const f2* bb, int a0, f2* xv){
  #pragma unroll
  for (int k = 0; k < 8; ++k){
    const float4 v = *(const float4*)(bb + (a0 ^ (k << 7)));
    xv[2*k] = f2{v.x, v.y}; xv[2*k+1] = f2{v.z, v.w};
  }
}
__device__ __forceinline__ void wrA(f2* bb, int a0, const f2* xv){
  #pragma unroll
  for (int k = 0; k < 8; ++k)
    *(float4*)(bb + (a0 ^ (k << 7))) = make_float4(xv[2*k].x, xv[2*k].y, xv[2*k+1].x, xv[2*k+1].y);
}
__device__ __forceinline__ void rdB(const f2* bb, int a0, f2* xv){
  #pragma unroll
  for (int k = 0; k < 8; ++k){
    const float4 v = *(const float4*)(bb + (a0 ^ ((k << 4) | (k << 1))));
    xv[2*k] = f2{v.x, v.y}; xv[2*k+1] = f2{v.z, v.w};
  }
}
__device__ __forceinline__ void wrB(f2* bb, int a0, const f2* xv){
  #pragma unroll
  for (int k = 0; k < 8; ++k)
    *(float4*)(bb + (a0 ^ ((k << 4) | (k << 1)))) = make_float4(xv[2*k].x, xv[2*k].y, xv[2*k+1].x, xv[2*k+1].y);
}
__device__ __forceinline__ void rdC(const f2* bb, int a0, f2* xv){
  #pragma unroll
  for (int k = 0; k < 8; ++k){
    const float4 v = *(const float4*)(bb + (a0 ^ (k << 1)));
    xv[2*k] = f2{v.x, v.y}; xv[2*k+1] = f2{v.z, v.w};
  }
}
__device__ __forceinline__ void wrC(f2* bb, int a0, const f2* xv){
  #pragma unroll
  for (int k = 0; k < 8; ++k)
    *(float4*)(bb + (a0 ^ (k << 1))) = make_float4(xv[2*k].x, xv[2*k].y, xv[2*k+1].x, xv[2*k+1].y);
}

__global__ void gate_prep(const float* __restrict__ w, float* __restrict__ gt){
  const int t = threadIdx.x;
  if (t >= 10) return;
  const float ha = 0.5f*w[t*4+0], hb = 0.5f*w[t*4+1];
  const float hg = 0.5f*w[t*4+2], hd = 0.5f*w[t*4+3];
  const float ca = cosf(ha), sa = sinf(ha);
  const float cb = cosf(hb), sb = sinf(hb);
  const float cg = cosf(hg), sg = sinf(hg);
  const float m00r = cb*ca, m00i =  sb*sa;
  const float m01r = -sb*ca, m01i = -cb*sa;
  const float m10r =  sb*ca, m10i = -cb*sa;
  const float m11r = cb*ca,  m11i = -sb*sa;
  gt[8*t+0] = cg*m00r + sg*m00i;  gt[8*t+1] = cg*m00i - sg*m00r;
  gt[8*t+2] = cg*m01r + sg*m01i;  gt[8*t+3] = cg*m01i - sg*m01r;
  gt[8*t+4] = cg*m10r - sg*m10i;  gt[8*t+5] = cg*m10i + sg*m10r;
  gt[8*t+6] = cg*m11r - sg*m11i;  gt[8*t+7] = cg*m11i + sg*m11r;
  gt[80+2*t] = cosf(hd); gt[81+2*t] = sinf(hd);
}

__global__ void __launch_bounds__(NT, 4)
qqk_kernel(const float* __restrict__ x, const float* __restrict__ gt,
           float* __restrict__ out)
{
  __shared__ __align__(16) f2 smem[1024];   // 8KB: one state buffer, one wave
  const int lane = threadIdx.x;             // 0..63
  f2* bb = smem;
  const f2* g2  = (const f2*)gt;
  const f2* gry = (const f2*)(gt + 80);
  const size_t e = (size_t)blockIdx.x;
  const float* xg = x + e * NFEAT;

  const int aA = (lane << 1) ^ ((lane >> 2) & 14);
  const int aB = ((lane >> 3) << 7) | ((lane & 7) << 1);
  const int aC = (lane << 4) ^ ((lane << 1) & 14);

  // twiddle constants T(e) = exp(+2pi i e/1024)
  const f2 T1c   = { 0.9999811752826011f, 0.0061358846491545f };
  const f2 T2c   = { 0.9999247018391445f, 0.0122715382857199f };
  const f2 T4c   = { 0.9996988186962042f, 0.0245412285229123f };
  const f2 T8c   = { 0.9987954562051724f, 0.0490676743274180f };
  const f2 T16c  = { 0.9951847266721969f, 0.0980171403295606f };
  const f2 T32c  = { 0.9807852804032304f, 0.1950903220161283f };
  const float c45 = 0.7071067811865476f, c22 = 0.9238795325112867f, s22 = 0.3826834323650898f;
  const f2 T64c  = { c22, s22 };
  const f2 T128c = { c45, c45 };

  f2 xrxi[10];
  f2 xv[16];
  // ---- P0: global float2 load + norm + gates q0,q1,q2 (bits 9,8,7) and q9 (bit 0); write A' ----
  float ss = 0.f;
  #pragma unroll
  for (int k = 0; k < 6; ++k){
    const float2 v = *(const float2*)(xg + (k << 7) + (lane << 1));
    xv[2*k] = f2{v.x, 0.f}; xv[2*k+1] = f2{v.y, 0.f};
    ss += v.x*v.x + v.y*v.y;
  }
  #pragma unroll
  for (int m = 12; m < 16; ++m) xv[m] = f2{0.f, 0.f};
  ss = dpp_add<0xB1>(ss); ss = dpp_add<0x4E>(ss);
  ss += __shfl_xor(ss, 4); ss += __shfl_xor(ss, 8); ss += __shfl_xor(ss, 16); ss += __shfl_xor(ss, 32);
  const float invn = 1.0f / fmaxf(sqrtf(ss), 1e-8f);
  #pragma unroll
  for (int m = 0; m < 12; ++m) xv[m].x *= invn;
  gate_on<8>(xv, g2+0); gate_on<4>(xv, g2+4); gate_on<2>(xv, g2+8); gate_on<1>(xv, g2+36);
  wrA(bb, aA, xv);
  MEMFENCE();
  // ---- P1: gates q3,q4,q5 (bits 6,5,4), layout B' ----
  rdB(bb, aB, xv);
  gate_on<8>(xv, g2+12); gate_on<4>(xv, g2+16); gate_on<2>(xv, g2+20);
  wrB(bb, aB, xv);
  MEMFENCE();
  // ---- P2: gates q6,q7,q8 (bits 3,2,1), layout C' ----
  rdC(bb, aC, xv);
  gate_on<8>(xv, g2+24); gate_on<4>(xv, g2+28); gate_on<2>(xv, g2+32);
  wrC(bb, aC, xv);
  MEMFENCE();
  // ---- P3: CNOT-ring gather (to C' slots) + RY q6,q7,q8,q9; write C' ----
  { const int ag = swz2(cnot_perm(lane << 4));
    #pragma unroll
    for (int m = 0; m < 16; ++m) xv[m] = bb[ag ^ swz2(cnot_perm(m))];
  }
  MEMFENCE();   // all gather reads precede the overwrites below (in-order DS)
  ry_on<8>(xv, gry[6]); ry_on<4>(xv, gry[7]); ry_on<2>(xv, gry[8]); ry_on<1>(xv, gry[9]);
  wrC(bb, aC, xv);
  MEMFENCE();
  // ---- P4: RY q0,q1,q2 + FFT stages bits 9,8,7 + EXPECTATIONS q9,q8,q7 (layout A') ----
  rdA(bb, aA, xv);
  ry_on<8>(xv, gry[0]); ry_on<4>(xv, gry[1]); ry_on<2>(xv, gry[2]);
  { float sa, ca; __sincosf((float)lane * 1.2271846303085130e-2f, &sa, &ca);  // BT = T(2*lane)
    const f2 BT = {ca, sa};
    const f2 BT2 = pk_cmul(BT, BT);
    const f2 BT4 = pk_cmul(BT2, BT2);
    f2 t9[8];
    t9[0] = BT;               t9[1] = pk_cmul(BT, T1c);
    t9[2] = pk_cmul(BT, T128c); t9[3] = pk_cmul(t9[1], T128c);
    t9[4] = rot90(t9[0]); t9[5] = rot90(t9[1]); t9[6] = rot90(t9[2]); t9[7] = rot90(t9[3]);
    #pragma unroll
    for (int m = 0; m < 8; ++m) bfly(xv[m], xv[m+8], t9[m]);        // stage bit 9
    f2 u[4];
    u[0] = BT2; u[1] = pk_cmul(BT2, T2c); u[2] = rot90(u[0]); u[3] = rot90(u[1]);
    #pragma unroll
    for (int m = 0; m < 16; ++m) if (!(m & 4)) bfly(xv[m], xv[m|4], u[m & 3]);   // bit 8
    f2 v2[2];
    v2[0] = BT4; v2[1] = pk_cmul(BT4, T4c);
    #pragma unroll
    for (int m = 0; m < 16; ++m) if (!(m & 2)) bfly(xv[m], xv[m|2], v2[m & 1]);  // bit 7
  }
  xrxi[9] = pairsum16<8>(xv) * 128.0f;   // missing 2^7 from remaining 7 stages
  xrxi[8] = pairsum16<4>(xv) * 128.0f;
  xrxi[7] = pairsum16<2>(xv) * 128.0f;
  wrA(bb, aA, xv);
  MEMFENCE();
  // ---- P5: RY q3,q4,q5 + FFT stages bits 6,5,4 + EXPECTATIONS q6,q5,q4 (layout B') ----
  rdB(bb, aB, xv);
  ry_on<8>(xv, gry[3]); ry_on<4>(xv, gry[4]); ry_on<2>(xv, gry[5]);
  { float sa, ca; __sincosf((float)(lane & 7) * 9.8174770424681035e-2f, &sa, &ca);  // CT = T(16*lane_l)
    const f2 CT = {ca, sa};
    const f2 CT2 = pk_cmul(CT, CT);
    const f2 CT4 = pk_cmul(CT2, CT2);
    f2 t6[8];
    t6[0] = CT;               t6[1] = pk_cmul(CT, T8c);
    t6[2] = pk_cmul(CT, T128c); t6[3] = pk_cmul(t6[1], T128c);
    t6[4] = rot90(t6[0]); t6[5] = rot90(t6[1]); t6[6] = rot90(t6[2]); t6[7] = rot90(t6[3]);
    #pragma unroll
    for (int m = 0; m < 8; ++m) bfly(xv[m], xv[m+8], t6[m]);        // stage bit 6
    f2 u[4];
    u[0] = CT2; u[1] = pk_cmul(CT2, T16c); u[2] = rot90(u[0]); u[3] = rot90(u[1]);
    #pragma unroll
    for (int m = 0; m < 16; ++m) if (!(m & 4)) bfly(xv[m], xv[m|4], u[m & 3]);   // bit 5
    f2 v2[2];
    v2[0] = CT4; v2[1] = pk_cmul(CT4, T32c);
    #pragma unroll
    for (int m = 0; m < 16; ++m) if (!(m & 2)) bfly(xv[m], xv[m|2], v2[m & 1]);  // bit 4
  }
  xrxi[6] = pairsum16<8>(xv) * 16.0f;    // missing 2^4 from remaining 4 stages
  xrxi[5] = pairsum16<4>(xv) * 16.0f;
  xrxi[4] = pairsum16<2>(xv) * 16.0f;
  wrB(bb, aB, xv);
  MEMFENCE();
  // ---- P6: FFT stages bits 3,2,1,0 + expectations q0..q3 + probabilities (layout C', NO write-back) ----
  rdC(bb, aC, xv);
  // stage bit 3: tw = T(64*m)
  bfly1(xv[0], xv[8]);
  bfly (xv[1], xv[9],  T64c);
  bfly (xv[2], xv[10], T128c);
  bfly (xv[3], xv[11], f2{ s22, c22});
  bflyI(xv[4], xv[12]);
  bfly (xv[5], xv[13], f2{-s22, c22});
  bfly (xv[6], xv[14], f2{-c45, c45});
  bfly (xv[7], xv[15], f2{-c22, s22});
  // stage bit 2: tw = T(128*(m&3))
  #pragma unroll
  for (int m = 0; m < 16; ++m) if (!(m & 4)){
    const int s = m & 3;
    if      (s == 0) bfly1(xv[m], xv[m|4]);
    else if (s == 1) bfly (xv[m], xv[m|4], T128c);
    else if (s == 2) bflyI(xv[m], xv[m|4]);
    else             bfly (xv[m], xv[m|4], f2{-c45, c45});
  }
  // stage bit 1: tw = {1, i}
  #pragma unroll
  for (int m = 0; m < 16; ++m) if (!(m & 2)){
    if (m & 1) bflyI(xv[m], xv[m|2]); else bfly1(xv[m], xv[m|2]);
  }
  // stage bit 0: tw = 1
  #pragma unroll
  for (int m = 0; m < 16; m += 2) bfly1(xv[m], xv[m+1]);
  xrxi[0] = pairsum16<1>(xv); xrxi[1] = pairsum16<2>(xv);
  xrxi[2] = pairsum16<4>(xv); xrxi[3] = pairsum16<8>(xv);
  float S = 0.f, z0 = 0.f, z1 = 0.f, z2 = 0.f, z3 = 0.f;
  #pragma unroll
  for (int m = 0; m < 16; ++m){
    const f2 q = pk_mul2(xv[m], xv[m]); const float n = q.x + q.y;
    S += n;
    z0 += (m & 1) ? -n : n;  z1 += (m & 2) ? -n : n;
    z2 += (m & 4) ? -n : n;  z3 += (m & 8) ? -n : n;
  }
  MEMFENCE();   // all state reads precede the reduction-row overwrite

  // ---- Walsh-Hadamard over lane bits on S -> Z4..Z9 ----
  float d0, d1, d2, d3, d4, d5;
  { float s = S, wv;
    wv = dpp_mov<0xB1>(s); d0 = (lane & 1)  ? (wv - s) : (s - wv); s += wv;
    wv = dpp_mov<0x4E>(s); d1 = (lane & 2)  ? (wv - s) : (s - wv); s += wv;
    wv = __shfl_xor(s, 4);  d2 = (lane & 4)  ? (wv - s) : (s - wv); s += wv;
    wv = __shfl_xor(s, 8);  d3 = (lane & 8)  ? (wv - s) : (s - wv); s += wv;
    wv = __shfl_xor(s, 16); d4 = (lane & 16) ? (wv - s) : (s - wv); s += wv;
    wv = __shfl_xor(s, 32); d5 = (lane & 32) ? (wv - s) : (s - wv); s += wv;
    d0 = dpp_add<0x4E>(d0); d0 += __shfl_xor(d0, 4); d0 += __shfl_xor(d0, 8); d0 += __shfl_xor(d0, 16); d0 += __shfl_xor(d0, 32);
    d1 += __shfl_xor(d1, 4); d1 += __shfl_xor(d1, 8); d1 += __shfl_xor(d1, 16); d1 += __shfl_xor(d1, 32);
    d2 += __shfl_xor(d2, 8); d2 += __shfl_xor(d2, 16); d2 += __shfl_xor(d2, 32);
    d3 += __shfl_xor(d3, 16); d3 += __shfl_xor(d3, 32);
    d4 += __shfl_xor(d4, 32);
  }

  // ---- quad pre-sum via DPP, then 24x17-stride float row transpose (conflict-free) ----
  #pragma unroll
  for (int q = 0; q < 10; ++q){
    xrxi[q].x = dpp_add<0x4E>(dpp_add<0xB1>(xrxi[q].x));
    xrxi[q].y = dpp_add<0x4E>(dpp_add<0xB1>(xrxi[q].y));
  }
  z0 = dpp_add<0x4E>(dpp_add<0xB1>(z0));
  z1 = dpp_add<0x4E>(dpp_add<0xB1>(z1));
  z2 = dpp_add<0x4E>(dpp_add<0xB1>(z2));
  z3 = dpp_add<0x4E>(dpp_add<0xB1>(z3));
  float* rb = (float*)bb;
  const int g = lane >> 2;
  if ((lane & 3) == 0){
    #pragma unroll
    for (int q = 0; q < 10; ++q){ rb[q*17 + g] = xrxi[q].x; rb[(10+q)*17 + g] = xrxi[q].y; }
    rb[20*17 + g] = z0; rb[21*17 + g] = z1; rb[22*17 + g] = z2; rb[23*17 + g] = z3;
  }
  MEMFENCE();   // row writes precede row reads (same-wave in-order DS)
  float* ob = out + e * 30;
  if (lane < 24){
    float acc = 0.f;
    #pragma unroll
    for (int gg = 0; gg < 16; ++gg) acc += rb[lane*17 + gg];
    ob[lane] = acc * ((lane < 20) ? (2.0f/1024.0f) : (1.0f/1024.0f));
  }
  if (lane == 0){
    const float zs = 1.0f/1024.0f;
    ob[24] = d0*zs; ob[25] = d1*zs; ob[26] = d2*zs;
    ob[27] = d3*zs; ob[28] = d4*zs; ob[29] = d5*zs;
  }
}

extern "C" void kernel_launch(void* const* d_in, const int* in_sizes, int n_in,
                              void* d_out, int out_size, void* d_ws, size_t ws_size,
                              hipStream_t stream) {
  const float* x = (const float*)d_in[0];
  const float* w = (const float*)d_in[1];
  float* out = (float*)d_out;
  float* gt  = (float*)d_ws;           // 100 floats of gate tables
  const int B = in_sizes[0] / NFEAT;   // 8192
  gate_prep<<<1, 16, 0, stream>>>(w, gt);
  qqk_kernel<<<B, NT, 0, stream>>>(x, gt, out);
}